// Round 6
// baseline (165.854 us; speedup 1.0000x reference)
//
#include <hip/hip_runtime.h>
#include <hip/hip_bf16.h>

typedef __attribute__((ext_vector_type(8)))  __bf16 bf16x8;
typedef __attribute__((ext_vector_type(16))) float  f32x16;
typedef __attribute__((ext_vector_type(4)))  float  f32x4;   // for nt stores

// Batched GEMM C[b] = A[b] @ B[b]^T, A:[B,N1,D] B:[B,N2,D] C:[B,N1,N2], D=64.
// Write-bound: 536 MB out. Observed ladder: store-run-length per 16KB-strided
// row is the lever (16B:215us, 512B:184us, 512B+nt:155us, linear fill:6.7TB/s).
// This round: tile reshaped 128x128 -> 32x512 so each C row gets a 2 KB
// contiguous run (4x longer). LDS staging + NT dwordx4 sweep kept. Bijective
// XCD swizzle keeps each batch's A+B panels (2 MB) inside one XCD L2.

static __device__ inline bf16x8 to_bf16x8(const float4& a, const float4& b) {
    bf16x8 r;
    r[0] = (__bf16)a.x; r[1] = (__bf16)a.y; r[2] = (__bf16)a.z; r[3] = (__bf16)a.w;
    r[4] = (__bf16)b.x; r[5] = (__bf16)b.y; r[6] = (__bf16)b.z; r[7] = (__bf16)b.w;
    return r;
}

__global__ __launch_bounds__(256) void MatrixAttention_76149770158251_kernel(
    const float* __restrict__ A, const float* __restrict__ Bm,
    float* __restrict__ C)
{
    const int N = 4096, D = 64;
    __shared__ float tile[32 * 512];        // 64 KB C-tile staging

    // ---- bijective XCD chunk swizzle: HW round-robins consecutive blocks
    // across the 8 XCDs; decode so XCD k owns batch k entirely.
    const int lin = blockIdx.x;             // 0..8191
    const int swz = (lin & 7) * 1024 + (lin >> 3);
    const int bz  = swz >> 10;              // batch 0..7
    const int wi  = swz & 1023;
    const int rg  = wi >> 3;                // row group 0..127 (32 rows each)
    const int cg  = wi & 7;                 // col group 0..7  (512 cols each)

    const int row0 = rg * 32;
    const int col0 = cg * 512;

    const int lane = threadIdx.x & 63;
    const int wid  = threadIdx.x >> 6;      // 0..3, wave owns 128 cols
    const int wc0  = col0 + wid * 128;

    const float* __restrict__ Ab = A  + (size_t)bz * N * D;
    const float* __restrict__ Bb = Bm + (size_t)bz * N * D;
    float* __restrict__ Cb       = C  + (size_t)bz * N * N;

    const int lrow  = lane & 31;
    const int khalf = (lane >> 5) * 8;

    // ---- A fragments (32 rows, shared by all waves): 4 K-steps
    bf16x8 af[4];
#pragma unroll
    for (int ks = 0; ks < 4; ++ks) {
        const float* p = Ab + (size_t)(row0 + lrow) * D + ks * 16 + khalf;
        float4 v0 = *(const float4*)(p);
        float4 v1 = *(const float4*)(p + 4);
        af[ks] = to_bf16x8(v0, v1);
    }

    // ---- B fragments: 4 col-frags x 4 K-steps for this wave's 128 cols
    bf16x8 bfr[4][4];
#pragma unroll
    for (int cf = 0; cf < 4; ++cf)
#pragma unroll
        for (int ks = 0; ks < 4; ++ks) {
            const float* p = Bb + (size_t)(wc0 + cf * 32 + lrow) * D + ks * 16 + khalf;
            float4 v0 = *(const float4*)(p);
            float4 v1 = *(const float4*)(p + 4);
            bfr[cf][ks] = to_bf16x8(v0, v1);
        }

    f32x16 acc[4];
#pragma unroll
    for (int cf = 0; cf < 4; ++cf) acc[cf] = (f32x16)0.0f;
#pragma unroll
    for (int cf = 0; cf < 4; ++cf)
#pragma unroll
        for (int ks = 0; ks < 4; ++ks)
            acc[cf] = __builtin_amdgcn_mfma_f32_32x32x16_bf16(
                af[ks], bfr[cf][ks], acc[cf], 0, 0, 0);

    // ---- stage acc -> LDS tile[32][512]
    // D layout (verified): col = lane&31, row = (v&3) + 8*(v>>2) + 4*(lane>>5)
#pragma unroll
    for (int cf = 0; cf < 4; ++cf) {
        const int col   = wid * 128 + cf * 32 + (lane & 31);
        const int rbase = 4 * (lane >> 5);
#pragma unroll
        for (int v = 0; v < 16; ++v) {
            const int r = rbase + (v & 3) + 8 * (v >> 2);
            tile[r * 512 + col] = acc[cf][v];
        }
    }

    __syncthreads();

    // ---- NT store sweep: each tile row = 2 KB contiguous run in C.
    const f32x4* t4 = (const f32x4*)tile;
    float* Cbase = Cb + (size_t)row0 * N + col0;
#pragma unroll
    for (int it = 0; it < 16; ++it) {
        const int f = it * 256 + threadIdx.x;    // float4 index, 128 per row
        const int r = f >> 7;
        const int c = f & 127;
        __builtin_nontemporal_store(t4[f], (f32x4*)(Cbase + (size_t)r * N + c * 4));
    }
}

extern "C" void kernel_launch(void* const* d_in, const int* in_sizes, int n_in,
                              void* d_out, int out_size, void* d_ws, size_t ws_size,
                              hipStream_t stream) {
    const float* m1 = (const float*)d_in[0];
    const float* m2 = (const float*)d_in[1];
    float* out = (float*)d_out;

    dim3 grid(8192);
    dim3 block(256);
    MatrixAttention_76149770158251_kernel<<<grid, block, 0, stream>>>(m1, m2, out);
}

// Round 7
// 156.686 us; speedup vs baseline: 1.0585x; 1.0585x over previous
//
#include <hip/hip_runtime.h>
#include <hip/hip_bf16.h>

typedef __attribute__((ext_vector_type(8)))  __bf16 bf16x8;
typedef __attribute__((ext_vector_type(16))) float  f32x16;
typedef __attribute__((ext_vector_type(4)))  float  f32x4;   // for nt stores

// Batched GEMM C[b] = A[b] @ B[b]^T, A:[B,N1,D] B:[B,N2,D] C:[B,N1,N2], D=64.
// Fabric-traffic model: L3-hit reads cost the same fabric BW as HBM traffic;
// only XCD-local L2 hits are free. R5 (128x128 + NT stores, no swizzle) moved
// 536MB writes + ~536MB L3-read re-fetches = 6.9 TB/s fabric == saturation.
// This round, SINGLE lever on the R5 structure: bijective batch-per-XCD
// swizzle -> each XCD's read working set = its batch's A+B = 4MB = its L2.
// Re-reads become L2 hits, fabric is left to the 536MB NT write stream.

static __device__ inline bf16x8 to_bf16x8(const float4& a, const float4& b) {
    bf16x8 r;
    r[0] = (__bf16)a.x; r[1] = (__bf16)a.y; r[2] = (__bf16)a.z; r[3] = (__bf16)a.w;
    r[4] = (__bf16)b.x; r[5] = (__bf16)b.y; r[6] = (__bf16)b.z; r[7] = (__bf16)b.w;
    return r;
}

__global__ __launch_bounds__(256) void MatrixAttention_76149770158251_kernel(
    const float* __restrict__ A, const float* __restrict__ Bm,
    float* __restrict__ C)
{
    const int N = 4096, D = 64;
    __shared__ float tile[128 * 128];       // 64 KB C-tile staging

    // ---- bijective XCD chunk swizzle (8192 blocks, 8192%8==0):
    // HW round-robins consecutive blockIdx across XCDs; decode so XCD k
    // executes exactly batch k (1024 blocks).
    const int lin = blockIdx.x;
    const int swz = (lin & 7) * 1024 + (lin >> 3);
    const int bz  = swz >> 10;              // batch 0..7
    const int bx  = swz & 31;               // col tile 0..31
    const int by  = (swz >> 5) & 31;        // row tile 0..31

    const int lane = threadIdx.x & 63;
    const int wid  = threadIdx.x >> 6;      // 0..3
    const int wr   = wid >> 1;              // 2x2 wave grid
    const int wc   = wid & 1;

    const int brow = by * 128;
    const int bcol = bx * 128;
    const int row0 = brow + wr * 64;
    const int col0 = bcol + wc * 64;

    const float* __restrict__ Ab = A  + (size_t)bz * N * D;
    const float* __restrict__ Bb = Bm + (size_t)bz * N * D;
    float* __restrict__ Cb       = C  + (size_t)bz * N * N;

    const int lrow  = lane & 31;            // row within 32-frag
    const int khalf = (lane >> 5) * 8;      // 0 or 8: K slice

    f32x16 acc[2][2];
#pragma unroll
    for (int i = 0; i < 2; ++i)
#pragma unroll
        for (int j = 0; j < 2; ++j) acc[i][j] = (f32x16)0.0f;

#pragma unroll
    for (int ks = 0; ks < 4; ++ks) {        // K = 64 = 4 * 16
        const int k = ks * 16 + khalf;
        bf16x8 af[2], bfr[2];
#pragma unroll
        for (int rb = 0; rb < 2; ++rb) {
            const float* p = Ab + (size_t)(row0 + rb * 32 + lrow) * D + k;
            float4 v0 = *(const float4*)(p);
            float4 v1 = *(const float4*)(p + 4);
            af[rb] = to_bf16x8(v0, v1);
        }
#pragma unroll
        for (int cb = 0; cb < 2; ++cb) {
            const float* p = Bb + (size_t)(col0 + cb * 32 + lrow) * D + k;
            float4 v0 = *(const float4*)(p);
            float4 v1 = *(const float4*)(p + 4);
            bfr[cb] = to_bf16x8(v0, v1);
        }
#pragma unroll
        for (int rb = 0; rb < 2; ++rb)
#pragma unroll
            for (int cb = 0; cb < 2; ++cb)
                acc[rb][cb] = __builtin_amdgcn_mfma_f32_32x32x16_bf16(
                    af[rb], bfr[cb], acc[rb][cb], 0, 0, 0);
    }

    // ---- stage acc -> LDS in block-tile coordinates
    // D layout (verified): col = lane&31, row = (v&3) + 8*(v>>2) + 4*(lane>>5)
#pragma unroll
    for (int rb = 0; rb < 2; ++rb)
#pragma unroll
        for (int cb = 0; cb < 2; ++cb) {
            const int col   = wc * 64 + cb * 32 + (lane & 31);
            const int rbase = wr * 64 + rb * 32 + 4 * (lane >> 5);
#pragma unroll
            for (int v = 0; v < 16; ++v) {
                const int r = rbase + (v & 3) + 8 * (v >> 2);
                tile[r * 128 + col] = acc[rb][cb][v];
            }
        }

    __syncthreads();

    // ---- NT store sweep (bypass L2/L3 allocation): 512B run per C row.
    const f32x4* t4 = (const f32x4*)tile;
    float* Cbase = Cb + (size_t)brow * N + bcol;
#pragma unroll
    for (int it = 0; it < 16; ++it) {
        const int f  = it * 256 + threadIdx.x;   // float4 index in tile
        const int r  = f >> 5;                   // 32 float4 per 128-col row
        const int cq = f & 31;
        __builtin_nontemporal_store(t4[f], (f32x4*)(Cbase + (size_t)r * N + cq * 4));
    }
}

extern "C" void kernel_launch(void* const* d_in, const int* in_sizes, int n_in,
                              void* d_out, int out_size, void* d_ws, size_t ws_size,
                              hipStream_t stream) {
    const float* m1 = (const float*)d_in[0];
    const float* m2 = (const float*)d_in[1];
    float* out = (float*)d_out;

    dim3 grid(8192);
    dim3 block(256);
    MatrixAttention_76149770158251_kernel<<<grid, block, 0, stream>>>(m1, m2, out);
}